// Round 8
// baseline (183.797 us; speedup 1.0000x reference)
//
#include <hip/hip_runtime.h>
#include <math.h>

#define BB   256
#define SS   512
#define VV   150
#define NPOS (BB * SS)        // 131072
#define GRID 2048
#define A_TASKS 4096          // 32 consecutive positions each
#define B_TASKS 4096          // 4096 float4 (64 KB) each
#define N_TASKS (A_TASKS + B_TASKS)
#define EPSF 1e-8f

// ws layout:
// [0,65536)           float4 pA[4096]  {gathered_sum, mask_cnt, eos_logp_sum, eos_cnt}
// [65536,81920)       float  pB[4096]  attention partials
// [81920,84992)       int    pC[768]   rep counts per (row,n)
// [84992,86016)       int    hasx[256] (has_t && !has_p) per row
// [86016,86024)       int    cnt[2]    {ab work counter, cf ticket} (memset to 0)
// [86272,217344)      uchar  toks[131072] argmax tokens

__device__ __forceinline__ unsigned long long akey(float f, int idx) {
    unsigned u = __float_as_uint(f);
    unsigned mono = ((int)u >= 0) ? (u | 0x80000000u) : ~u;   // order-preserving
    return ((unsigned long long)mono << 8) | (unsigned)(255 - idx);
}
__device__ __forceinline__ unsigned long long kmax(unsigned long long a,
                                                   unsigned long long b) {
    return a > b ? a : b;
}

__global__ __launch_bounds__(256) void kern_ab(
    const float* __restrict__ pred, const int* __restrict__ tgt,
    const float* __restrict__ attw, float4* __restrict__ pA,
    float* __restrict__ pB, unsigned char* __restrict__ toks,
    int* __restrict__ cnt)
{
    __shared__ int stask;
    const int tid  = threadIdx.x;
    const int lane = tid & 63;
    const int w    = tid >> 6;

    for (;;) {
        __syncthreads();                       // protect stask reuse
        if (tid == 0) stask = atomicAdd(cnt, 1);
        __syncthreads();
        const int task = stask;
        if (task >= N_TASKS) break;

        if (task < A_TASKS) {
            // ---- A task: 32 consecutive positions, this wave does 8 ----
            const int pbase = task * 32 + w * 8;
            float sg = 0.f, smc = 0.f, sel = 0.f, sec = 0.f;  // lane0 only
            unsigned long long tok8 = 0;
            for (int p = 0; p < 8; ++p) {
                const int pos = pbase + p;
                const float* row = pred + (size_t)pos * VV;
                const float v0 = row[lane];
                const float v1 = row[lane + 64];
                const bool  l3 = lane < (VV - 128);           // 22 lanes
                const float v2 = l3 ? row[lane + 128] : 0.f;

                unsigned long long k = kmax(akey(v0, lane), akey(v1, lane + 64));
                if (l3) k = kmax(k, akey(v2, lane + 128));
                #pragma unroll
                for (int off = 32; off > 0; off >>= 1)
                    k = kmax(k, __shfl_xor(k, off));
                const int li = 255 - (int)(k & 0xFF);

                const int t = tgt[pos];                       // wave-uniform
                const float src = (t < 64) ? v0 : (t < 128) ? v1 : v2;
                const float g = __shfl(src, t & 63);

                if (t == 2) {                                 // rare, uniform
                    const unsigned mono = (unsigned)(k >> 8);
                    const unsigned fb = (mono & 0x80000000u) ? (mono & 0x7FFFFFFFu)
                                                             : ~mono;
                    const float m = __uint_as_float(fb);
                    float ex = __expf(v0 - m) + __expf(v1 - m)
                             + (l3 ? __expf(v2 - m) : 0.f);
                    #pragma unroll
                    for (int off = 32; off > 0; off >>= 1)
                        ex += __shfl_xor(ex, off);
                    const float p2 = __shfl(v0, 2);
                    if (lane == 0) {
                        sel += __logf(__expf(p2 - m) / ex + EPSF);
                        sec += 1.f;
                    }
                }
                if (lane == 0) {
                    tok8 |= (unsigned long long)li << (8 * p);
                    if (t != 0) { sg += g; smc += 1.f; }
                }
            }
            if (lane == 0) {
                *(unsigned long long*)(toks + pbase) = tok8;
                // per-wave slot: task covers 4 waves -> pA[task] built from
                // 4 wave-quadrant writes via float4 per wave? Use one slot per
                // wave-quarter: pack into pA[task] with atomic-free scheme:
                // each wave writes its own quarter-slot.
            }
            // combine 4 waves' partials into pA[task] (fixed content per task)
            __shared__ float red[4][4];
            if (lane == 0) {
                red[w][0] = sg; red[w][1] = smc; red[w][2] = sel; red[w][3] = sec;
            }
            __syncthreads();
            if (tid == 0) {
                float4 r;
                r.x = red[0][0] + red[1][0] + red[2][0] + red[3][0];
                r.y = red[0][1] + red[1][1] + red[2][1] + red[3][1];
                r.z = red[0][2] + red[1][2] + red[2][2] + red[3][2];
                r.w = red[0][3] + red[1][3] + red[2][3] + red[3][3];
                pA[task] = r;
            }
        } else {
            // ---- B task: 4096 float4 contiguous (64 KB) ----
            const int j = task - A_TASKS;
            const float4* a4 = (const float4*)attw;
            const size_t base = (size_t)j * 4096;
            float s0 = 0.f, s1 = 0.f;
            #pragma unroll
            for (int k = 0; k < 16; k += 2) {
                const float4 x = a4[base + (size_t)k * 256 + tid];
                const float4 y = a4[base + (size_t)(k + 1) * 256 + tid];
                s0 += x.x * __logf(x.x + EPSF) + x.y * __logf(x.y + EPSF)
                    + x.z * __logf(x.z + EPSF) + x.w * __logf(x.w + EPSF);
                s1 += y.x * __logf(y.x + EPSF) + y.y * __logf(y.y + EPSF)
                    + y.z * __logf(y.z + EPSF) + y.w * __logf(y.w + EPSF);
            }
            float s = s0 + s1;
            #pragma unroll
            for (int off = 32; off > 0; off >>= 1) s += __shfl_xor(s, off);
            __shared__ float redb[4];
            if (lane == 0) redb[w] = s;
            __syncthreads();
            if (tid == 0) pB[j] = redb[0] + redb[1] + redb[2] + redb[3];
        }
    }
}

// ---- n-gram penalty (768 blocks) + last-block final reduce ----
__global__ __launch_bounds__(256) void kern_cf(
    const unsigned char* __restrict__ toks, const int* __restrict__ tgt,
    int* __restrict__ pC, int* __restrict__ hasx, int* __restrict__ counter,
    const float4* __restrict__ pA, const float* __restrict__ pB,
    float* __restrict__ out)
{
    const int blk = blockIdx.x;
    const int b = blk & 255;
    const int n = 2 + (blk >> 8);
    const int L = SS - n + 1;
    const int tid = threadIdx.x;

    __shared__ int tok[SS];
    __shared__ __align__(16) int h[SS];
    __shared__ int sflags;
    __shared__ int sticket;

    if (tid == 0) sflags = 0;
    const unsigned char* rt = toks + b * SS;
    tok[tid]       = rt[tid];
    tok[tid + 256] = rt[tid + 256];
    __syncthreads();

    if (blk < 256) {
        const int* trow = tgt + b * SS;
        int f = 0;
        if (trow[tid] == 2 || trow[tid + 256] == 2) f |= 1;
        if (tok[tid] == 2 || tok[tid + 256] == 2)   f |= 2;
        if (f) atomicOr(&sflags, f);
    }

    #pragma unroll
    for (int q = 0; q < 2; ++q) {
        const int i = tid + q * 256;
        int hv;
        if (i < L) {
            hv = tok[i];
            int mul = VV;
            for (int j = 1; j < n; ++j) { hv += tok[i + j] * mul; mul *= VV; }
        } else {
            hv = 0x7F000000 + i;   // unique sentinel, > any real hash (~5.06e8)
        }
        h[i] = hv;
    }
    __syncthreads();

    const int i1 = tid, i2 = tid + 256;
    const int h1 = h[i1], h2 = h[i2];
    int c1 = 0, c2 = 0;
    #pragma unroll 4
    for (int j = 0; j < SS; j += 4) {
        const int4 hv = *(const int4*)&h[j];
        c1 += (hv.x == h1 && j     < i1) + (hv.y == h1 && j + 1 < i1)
            + (hv.z == h1 && j + 2 < i1) + (hv.w == h1 && j + 3 < i1);
        c2 += (hv.x == h2 && j     < i2) + (hv.y == h2 && j + 1 < i2)
            + (hv.z == h2 && j + 2 < i2) + (hv.w == h2 && j + 3 < i2);
    }
    int rep = (c1 >= 2) + (c2 >= 2);
    #pragma unroll
    for (int off = 32; off > 0; off >>= 1) rep += __shfl_xor(rep, off);
    __shared__ int w4[4];
    if ((tid & 63) == 0) w4[tid >> 6] = rep;
    __syncthreads();
    if (tid == 0) {
        pC[blk] = w4[0] + w4[1] + w4[2] + w4[3];
        if (blk < 256) hasx[b] = ((sflags & 1) && !(sflags & 2)) ? 1 : 0;
        __threadfence();                      // publish before ticket
        sticket = atomicAdd(counter, 1);
    }
    __syncthreads();
    if (sticket != 768 - 1) return;

    // ---- last block: final reduce (deterministic: fixed-order sums) ----
    __threadfence();                          // acquire others' pC/hasx
    const int lane = tid & 63;
    const int wid  = tid >> 6;
    double v[9];
    #pragma unroll
    for (int k = 0; k < 9; ++k) v[k] = 0.0;
    for (int i = tid; i < A_TASKS; i += 256) {
        const float4 p = pA[i];
        v[0] += p.x; v[1] += p.y; v[2] += p.z; v[3] += p.w;
    }
    for (int i = tid; i < B_TASKS; i += 256) v[4] += pB[i];
    v[5] = pC[tid]; v[6] = pC[tid + 256]; v[7] = pC[tid + 512];
    v[8] = (double)hasx[tid];

    #pragma unroll
    for (int off = 32; off > 0; off >>= 1)
        #pragma unroll
        for (int k = 0; k < 9; ++k) v[k] += __shfl_xor(v[k], off);

    __shared__ double sd[4][9];
    if (lane == 0)
        for (int k = 0; k < 9; ++k) sd[wid][k] = v[k];
    __syncthreads();

    if (tid == 0) {
        double r[9];
        for (int k = 0; k < 9; ++k) r[k] = sd[0][k] + sd[1][k] + sd[2][k] + sd[3][k];
        const double mainv    = -r[0] / fmax(r[1], 1.0);
        const double eos_loss = (r[3] > 0.0) ? (-r[2] / (double)NPOS) : 0.0;
        const double no_eos   = r[8] / (double)BB;
        const double eos_tot  = eos_loss + 0.5 * no_eos;
        const double att      = 0.1 * r[4] / (double)NPOS;  // = -mean(ent)*0.1
        const double pattern  = (0.2 * r[5] + 0.3 * r[6] + 0.4 * r[7]) / (double)BB;
        const double total    = mainv + 0.1 * pattern + 0.2 * eos_tot + 0.05 * att;
        out[0] = (float)total;   out[1] = (float)mainv; out[2] = (float)pattern;
        out[3] = (float)eos_tot; out[4] = (float)att;
    }
}

extern "C" void kernel_launch(void* const* d_in, const int* in_sizes, int n_in,
                              void* d_out, int out_size, void* d_ws, size_t ws_size,
                              hipStream_t stream)
{
    const float* pred = (const float*)d_in[0];
    const int*   tgt  = (const int*)d_in[1];
    const float* attw = (const float*)d_in[2];
    float* out = (float*)d_out;
    char*  ws  = (char*)d_ws;

    float4* pA   = (float4*)ws;
    float*  pB   = (float*)(ws + 65536);
    int*    pC   = (int*)(ws + 81920);
    int*    hasx = (int*)(ws + 84992);
    int*    cnt  = (int*)(ws + 86016);
    unsigned char* toks = (unsigned char*)(ws + 86272);

    hipMemsetAsync(cnt, 0, 8, stream);   // zero {work counter, cf ticket}
    kern_ab<<<GRID, 256, 0, stream>>>(pred, tgt, attw, pA, pB, toks, cnt);
    kern_cf<<<768, 256, 0, stream>>>(toks, tgt, pC, hasx, cnt + 1, pA, pB, out);
}

// Round 9
// 118.196 us; speedup vs baseline: 1.5550x; 1.5550x over previous
//
#include <hip/hip_runtime.h>
#include <math.h>

#define BB   256
#define SS   512
#define VV   150
#define NPOS (BB * SS)        // 131072
#define A_BLOCKS 512          // 256 positions each (8 iters x 32 rows)
#define B_BLOCKS 2048         // 8192 float4 (131 KB) each
#define GRID (A_BLOCKS + B_BLOCKS)   // 2560
#define EPSF 1e-8f

// ws layout:
// [0,8192)        float4 pA[512]
// [8192,16384)    float  pB[2048]
// [16384,19456)   int    pC[768]
// [19456,20480)   int    hasx[256]
// [20480,20484)   int    cnt (cf ticket, memset 0)
// [20736,151808)  uchar  toks[131072]

__global__ __launch_bounds__(256) void kern_ab(
    const float* __restrict__ pred, const int* __restrict__ tgt,
    const float* __restrict__ attw, float4* __restrict__ pA,
    float* __restrict__ pB, unsigned char* __restrict__ toks)
{
    __shared__ __align__(16) float slab[32 * VV];   // 19.2 KB
    __shared__ float red[4][4];
    const int tid  = threadIdx.x;
    const int lane = tid & 63;
    const int w    = tid >> 6;
    const int bid  = blockIdx.x;

    if (bid % 5 == 0) {
        // ================= A-role: predictions =================
        const int a_idx = bid / 5;                  // 0..511
        float acc_g = 0.f, acc_mc = 0.f, acc_el = 0.f, acc_ec = 0.f;
        const int p = tid >> 3;                     // row in batch (0..31)
        const int s = tid & 7;                      // segment
        const int c0 = s * 19;
        const int ncol = (c0 + 19 <= VV) ? 19 : (VV - c0);   // 19 or 17

        for (int it = 0; it < 8; ++it) {
            if (it) __syncthreads();
            const int rbase = a_idx * 256 + it * 32;
            // stage 32 rows = 1200 float4, coalesced
            const float4* g4 = (const float4*)(pred + (size_t)rbase * VV);
            float4* l4 = (float4*)slab;
            #pragma unroll
            for (int k = 0; k < 5; ++k) {
                const int i = tid + k * 256;
                if (i < 1200) l4[i] = g4[i];
            }
            __syncthreads();

            const float* row = slab + p * VV;
            float m = -INFINITY; int mi = 200;
            #pragma unroll
            for (int j = 0; j < 19; ++j) {
                if (j < ncol) {
                    const float f = row[c0 + j];
                    if (f > m) { m = f; mi = c0 + j; }
                }
            }
            #pragma unroll
            for (int off = 1; off <= 4; off <<= 1) {
                const float om = __shfl_xor(m, off);
                const int   oi = __shfl_xor(mi, off);
                if (om > m || (om == m && oi < mi)) { m = om; mi = oi; }
            }

            const int t = tgt[rbase + p];           // uniform in 8-lane group
            if (t != 0) {
                if (s == t / 19) acc_g += row[t];
                if (s == 0)      acc_mc += 1.f;
            }
            if (t == 2) {                           // group-uniform branch
                float sx = 0.f;
                #pragma unroll
                for (int j = 0; j < 19; ++j)
                    if (j < ncol) sx += __expf(row[c0 + j] - m);
                #pragma unroll
                for (int off = 1; off <= 4; off <<= 1)
                    sx += __shfl_xor(sx, off);
                if (s == 0) {
                    acc_el += __logf(__expf(row[2] - m) / sx + EPSF);
                    acc_ec += 1.f;
                }
            }
            if (s == 0) toks[rbase + p] = (unsigned char)mi;
        }

        #pragma unroll
        for (int off = 32; off > 0; off >>= 1) {
            acc_g  += __shfl_xor(acc_g,  off);
            acc_mc += __shfl_xor(acc_mc, off);
            acc_el += __shfl_xor(acc_el, off);
            acc_ec += __shfl_xor(acc_ec, off);
        }
        if (lane == 0) {
            red[w][0] = acc_g; red[w][1] = acc_mc;
            red[w][2] = acc_el; red[w][3] = acc_ec;
        }
        __syncthreads();
        if (tid == 0) {
            float4 r;
            r.x = red[0][0] + red[1][0] + red[2][0] + red[3][0];
            r.y = red[0][1] + red[1][1] + red[2][1] + red[3][1];
            r.z = red[0][2] + red[1][2] + red[2][2] + red[3][2];
            r.w = red[0][3] + red[1][3] + red[2][3] + red[3][3];
            pA[a_idx] = r;
        }
    } else {
        // ================= B-role: attention entropy =================
        const int j = bid - bid / 5 - 1;            // 0..2047
        const float4* a4 = (const float4*)attw;
        const size_t base = (size_t)j * 8192;
        float s0 = 0.f, s1 = 0.f;
        for (int k = 0; k < 32; k += 8) {
            float4 v[8];
            #pragma unroll
            for (int q = 0; q < 8; ++q)
                v[q] = a4[base + (size_t)(k + q) * 256 + tid];
            #pragma unroll
            for (int q = 0; q < 8; ++q) {
                float& acc = (q & 1) ? s1 : s0;
                acc += v[q].x * __logf(v[q].x + EPSF)
                     + v[q].y * __logf(v[q].y + EPSF)
                     + v[q].z * __logf(v[q].z + EPSF)
                     + v[q].w * __logf(v[q].w + EPSF);
            }
        }
        float s = s0 + s1;
        #pragma unroll
        for (int off = 32; off > 0; off >>= 1) s += __shfl_xor(s, off);
        if (lane == 0) red[w][0] = s;
        __syncthreads();
        if (tid == 0) pB[j] = red[0][0] + red[1][0] + red[2][0] + red[3][0];
    }
}

// ---- n-gram penalty (768 blocks) + last-block final reduce ----
__global__ __launch_bounds__(256) void kern_cf(
    const unsigned char* __restrict__ toks, const int* __restrict__ tgt,
    int* __restrict__ pC, int* __restrict__ hasx, int* __restrict__ counter,
    const float4* __restrict__ pA, const float* __restrict__ pB,
    float* __restrict__ out)
{
    const int blk = blockIdx.x;
    const int b = blk & 255;
    const int n = 2 + (blk >> 8);
    const int L = SS - n + 1;
    const int tid = threadIdx.x;

    __shared__ int tok[SS];
    __shared__ __align__(16) int h[SS];
    __shared__ int sflags;
    __shared__ int sticket;

    if (tid == 0) sflags = 0;
    const unsigned char* rt = toks + b * SS;
    tok[tid]       = rt[tid];
    tok[tid + 256] = rt[tid + 256];
    __syncthreads();

    if (blk < 256) {
        const int* trow = tgt + b * SS;
        int f = 0;
        if (trow[tid] == 2 || trow[tid + 256] == 2) f |= 1;
        if (tok[tid] == 2 || tok[tid + 256] == 2)   f |= 2;
        if (f) atomicOr(&sflags, f);
    }

    #pragma unroll
    for (int q = 0; q < 2; ++q) {
        const int i = tid + q * 256;
        int hv;
        if (i < L) {
            hv = tok[i];
            int mul = VV;
            for (int j = 1; j < n; ++j) { hv += tok[i + j] * mul; mul *= VV; }
        } else {
            hv = 0x7F000000 + i;   // unique sentinel, > any real hash (~5.06e8)
        }
        h[i] = hv;
    }
    __syncthreads();

    const int i1 = tid, i2 = tid + 256;
    const int h1 = h[i1], h2 = h[i2];
    int c1 = 0, c2 = 0;
    #pragma unroll 4
    for (int j = 0; j < SS; j += 4) {
        const int4 hv = *(const int4*)&h[j];
        c1 += (hv.x == h1 && j     < i1) + (hv.y == h1 && j + 1 < i1)
            + (hv.z == h1 && j + 2 < i1) + (hv.w == h1 && j + 3 < i1);
        c2 += (hv.x == h2 && j     < i2) + (hv.y == h2 && j + 1 < i2)
            + (hv.z == h2 && j + 2 < i2) + (hv.w == h2 && j + 3 < i2);
    }
    int rep = (c1 >= 2) + (c2 >= 2);
    #pragma unroll
    for (int off = 32; off > 0; off >>= 1) rep += __shfl_xor(rep, off);
    __shared__ int w4[4];
    if ((tid & 63) == 0) w4[tid >> 6] = rep;
    __syncthreads();
    if (tid == 0) {
        pC[blk] = w4[0] + w4[1] + w4[2] + w4[3];
        if (blk < 256) hasx[b] = ((sflags & 1) && !(sflags & 2)) ? 1 : 0;
        __threadfence();                      // publish before ticket
        sticket = atomicAdd(counter, 1);
    }
    __syncthreads();
    if (sticket != 768 - 1) return;

    // ---- last block: final reduce (deterministic: fixed-order sums) ----
    __threadfence();                          // acquire others' pC/hasx
    const int lane = tid & 63;
    const int wid  = tid >> 6;
    double v[9];
    #pragma unroll
    for (int k = 0; k < 9; ++k) v[k] = 0.0;
    for (int i = tid; i < A_BLOCKS; i += 256) {
        const float4 p = pA[i];
        v[0] += p.x; v[1] += p.y; v[2] += p.z; v[3] += p.w;
    }
    for (int i = tid; i < B_BLOCKS; i += 256) v[4] += pB[i];
    v[5] = pC[tid]; v[6] = pC[tid + 256]; v[7] = pC[tid + 512];
    v[8] = (double)hasx[tid];

    #pragma unroll
    for (int off = 32; off > 0; off >>= 1)
        #pragma unroll
        for (int k = 0; k < 9; ++k) v[k] += __shfl_xor(v[k], off);

    __shared__ double sd[4][9];
    if (lane == 0)
        for (int k = 0; k < 9; ++k) sd[wid][k] = v[k];
    __syncthreads();

    if (tid == 0) {
        double r[9];
        for (int k = 0; k < 9; ++k) r[k] = sd[0][k] + sd[1][k] + sd[2][k] + sd[3][k];
        const double mainv    = -r[0] / fmax(r[1], 1.0);
        const double eos_loss = (r[3] > 0.0) ? (-r[2] / (double)NPOS) : 0.0;
        const double no_eos   = r[8] / (double)BB;
        const double eos_tot  = eos_loss + 0.5 * no_eos;
        const double att      = 0.1 * r[4] / (double)NPOS;  // = -mean(ent)*0.1
        const double pattern  = (0.2 * r[5] + 0.3 * r[6] + 0.4 * r[7]) / (double)BB;
        const double total    = mainv + 0.1 * pattern + 0.2 * eos_tot + 0.05 * att;
        out[0] = (float)total;   out[1] = (float)mainv; out[2] = (float)pattern;
        out[3] = (float)eos_tot; out[4] = (float)att;
    }
}

extern "C" void kernel_launch(void* const* d_in, const int* in_sizes, int n_in,
                              void* d_out, int out_size, void* d_ws, size_t ws_size,
                              hipStream_t stream)
{
    const float* pred = (const float*)d_in[0];
    const int*   tgt  = (const int*)d_in[1];
    const float* attw = (const float*)d_in[2];
    float* out = (float*)d_out;
    char*  ws  = (char*)d_ws;

    float4* pA   = (float4*)ws;
    float*  pB   = (float*)(ws + 8192);
    int*    pC   = (int*)(ws + 16384);
    int*    hasx = (int*)(ws + 19456);
    int*    cnt  = (int*)(ws + 20480);
    unsigned char* toks = (unsigned char*)(ws + 20736);

    hipMemsetAsync(cnt, 0, 4, stream);   // zero cf ticket
    kern_ab<<<GRID, 256, 0, stream>>>(pred, tgt, attw, pA, pB, toks);
    kern_cf<<<768, 256, 0, stream>>>(toks, tgt, pC, hasx, cnt, pA, pB, out);
}